// Round 1
// baseline (925.582 us; speedup 1.0000x reference)
//
#include <hip/hip_runtime.h>
#include <hip/hip_bf16.h>
#include <stdint.h>

#define NN 40000
#define EE 640000
#define GG 256
#define FFE 9
#define HH 128

typedef __bf16 bf16;
typedef __bf16 bf16x8 __attribute__((ext_vector_type(8)));
typedef float f32x4 __attribute__((ext_vector_type(4)));

__device__ __forceinline__ f32x4 mfma16(bf16x8 a, bf16x8 b, f32x4 c){
  return __builtin_amdgcn_mfma_f32_16x16x32_bf16(a, b, c, 0, 0, 0);
}
__device__ __forceinline__ float silu_f(float x){ return x / (1.0f + __expf(-x)); }

// ---------------- weight prep: f32 [k][n] -> bf16 [n][k] ----------------
__global__ __launch_bounds__(256) void k_transpose_bf16(
    const float* __restrict__ src, bf16* __restrict__ dst,
    int R, int C, long sls, long dls)
{
  int l = blockIdx.y;
  int idx = blockIdx.x*256 + threadIdx.x;
  if (idx >= R*C) return;
  int n = idx / R, k = idx % R;
  dst[(long)l*dls + (long)n*R + k] = (bf16)src[(long)l*sls + (long)k*C + n];
}

// ---------------- embedding: h = x @ emb_w + emb_b ----------------
__global__ __launch_bounds__(256) void k_emb(
    const float* __restrict__ x, const float* __restrict__ w,
    const float* __restrict__ b, float* __restrict__ h)
{
  int idx = blockIdx.x*256 + threadIdx.x;
  int n = idx >> 7, f = idx & 127;
  float s = b[f];
  const float* xr = x + n*FFE;
  #pragma unroll
  for (int k=0;k<FFE;++k) s += xr[k]*w[k*HH + f];
  h[idx] = s;
}

// ---------------- counting sort by dst ----------------
__global__ __launch_bounds__(256) void k_hist(const int* __restrict__ dst, int* __restrict__ cnt){
  int e = blockIdx.x*256 + threadIdx.x;
  if (e < EE) atomicAdd(&cnt[dst[e]], 1);
}

__global__ __launch_bounds__(1024) void k_scan(const int* __restrict__ cnt, int* __restrict__ cursor, int n){
  __shared__ int s_wsum[16];
  __shared__ int s_run;
  int tid = threadIdx.x, lane = tid & 63, wv = tid >> 6;
  if (tid == 0) s_run = 0;
  __syncthreads();
  for (int base=0; base<n; base+=1024){
    int i = base + tid;
    int v = (i<n)? cnt[i] : 0;
    int x = v;
    #pragma unroll
    for (int off=1; off<64; off<<=1){ int t = __shfl_up(x, off); if (lane>=off) x += t; }
    if (lane==63) s_wsum[wv] = x;
    __syncthreads();
    if (wv==0 && lane<16){
      int y = s_wsum[lane];
      #pragma unroll
      for (int off=1; off<16; off<<=1){ int t = __shfl_up(y, off, 16); if (lane>=off) y += t; }
      s_wsum[lane] = y;
    }
    __syncthreads();
    int woff = wv ? s_wsum[wv-1] : 0;
    int run = s_run;
    if (i<n) cursor[i] = run + woff + x - v;
    __syncthreads();
    if (tid==0) s_run = run + s_wsum[15];
    __syncthreads();
  }
}

__global__ __launch_bounds__(256) void k_scatter(
    const int* __restrict__ ei, const float* __restrict__ pos,
    int* __restrict__ cursor, int* __restrict__ src_s,
    int* __restrict__ dst_s, float* __restrict__ dist_s)
{
  int e = blockIdx.x*256 + threadIdx.x;
  if (e >= EE) return;
  int s = ei[e], d = ei[EE + e];
  int p = atomicAdd(&cursor[d], 1);
  src_s[p] = s; dst_s[p] = d;
  float dx = pos[d*3+0]-pos[s*3+0];
  float dy = pos[d*3+1]-pos[s*3+1];
  float dz = pos[d*3+2]-pos[s*3+2];
  dist_s[p] = sqrtf(dx*dx+dy*dy+dz*dz);
}

// ---------------- generic 64x64-tile bf16 MFMA GEMM ----------------
// out[M][Nw] = act(A @ WT' + bias) (+resid); WT stored [Nw][KTOT] bf16.
template<int KTOT, int K1, int ACT, bool ABF, bool BIAS, bool RESID, bool OBF, bool OF>
__global__ __launch_bounds__(256) void k_gemm(
    const void* __restrict__ a1v, const float* __restrict__ a2,
    const bf16* __restrict__ wt, const float* __restrict__ bias,
    const float* __restrict__ resid, bf16* __restrict__ outb,
    float* __restrict__ outf, int Nw)
{
  constexpr int LDK = 136;
  __shared__ bf16 s_a[64*LDK];
  __shared__ bf16 s_w[64*LDK];
  int tid = threadIdx.x, lane = tid & 63, w = tid >> 6;
  int m0 = blockIdx.x*64, n0 = blockIdx.y*64;
  int wm = (w>>1)*32, wn = (w&1)*32;
  f32x4 acc[2][2];
  #pragma unroll
  for (int i=0;i<2;++i){
    #pragma unroll
    for (int j=0;j<2;++j){
      #pragma unroll
      for (int r=0;r<4;++r) acc[i][j][r]=0.f;
    }
  }
  int rsel = lane & 15, ksel = (lane>>4)*8;

  for (int kh=0; kh<KTOT; kh+=128){
    #pragma unroll
    for (int it=0; it<4; ++it){
      int idx = tid + it*256;
      int row = idx >> 4, col = (idx & 15)*8;
      int gc = kh + col;
      bf16x8 vv;
      if (ABF){
        vv = *(const bf16x8*)((const bf16*)a1v + (size_t)(m0+row)*K1 + gc);
      } else {
        const float* srcp;
        if (gc < K1) srcp = (const float*)a1v + (size_t)(m0+row)*K1 + gc;
        else         srcp = a2 + (size_t)(m0+row)*(KTOT-K1) + (gc-K1);
        f32x4 u0 = *(const f32x4*)srcp;
        f32x4 u1 = *(const f32x4*)(srcp+4);
        vv[0]=(bf16)u0[0]; vv[1]=(bf16)u0[1]; vv[2]=(bf16)u0[2]; vv[3]=(bf16)u0[3];
        vv[4]=(bf16)u1[0]; vv[5]=(bf16)u1[1]; vv[6]=(bf16)u1[2]; vv[7]=(bf16)u1[3];
      }
      *(bf16x8*)&s_a[row*LDK + col] = vv;
      *(bf16x8*)&s_w[row*LDK + col] = *(const bf16x8*)(wt + (size_t)(n0+row)*KTOT + gc);
    }
    __syncthreads();
    #pragma unroll
    for (int ks=0; ks<4; ++ks){
      int kb = ks*32 + ksel;
      bf16x8 fa0 = *(const bf16x8*)&s_a[(wm+rsel)*LDK + kb];
      bf16x8 fa1 = *(const bf16x8*)&s_a[(wm+16+rsel)*LDK + kb];
      bf16x8 fb0 = *(const bf16x8*)&s_w[(wn+rsel)*LDK + kb];
      bf16x8 fb1 = *(const bf16x8*)&s_w[(wn+16+rsel)*LDK + kb];
      acc[0][0]=mfma16(fa0,fb0,acc[0][0]);
      acc[0][1]=mfma16(fa0,fb1,acc[0][1]);
      acc[1][0]=mfma16(fa1,fb0,acc[1][0]);
      acc[1][1]=mfma16(fa1,fb1,acc[1][1]);
    }
    __syncthreads();
  }

  #pragma unroll
  for (int i=0;i<2;++i){
    #pragma unroll
    for (int j=0;j<2;++j){
      int col = n0 + wn + j*16 + (lane&15);
      float bv = BIAS ? bias[col] : 0.0f;
      #pragma unroll
      for (int r=0;r<4;++r){
        int row = m0 + wm + i*16 + 4*(lane>>4) + r;
        float v = acc[i][j][r] + bv;
        if (ACT==1) v = silu_f(v);
        if (RESID) v += resid[(size_t)row*Nw + col];
        if (OBF) outb[(size_t)row*Nw + col] = (bf16)v;
        if (OF)  outf[(size_t)row*Nw + col] = v;
      }
    }
  }
}

// ---------------- fused edge MLP + segmented aggregation ----------------
// P: [N][256] bf16 (A-part | B-part). Edges pre-sorted by dst.
__global__ __launch_bounds__(256) void k_edge(
    const bf16* __restrict__ P, const bf16* __restrict__ w2t,
    const float* __restrict__ w1r, const float* __restrict__ b1,
    const float* __restrict__ b2,
    const int* __restrict__ src_s, const int* __restrict__ dst_s,
    const float* __restrict__ dist_s, float* __restrict__ aggr)
{
  __shared__ bf16 s_m1[64*136];
  __shared__ bf16 s_w2[128*136];
  __shared__ int s_dst[64];
  __shared__ int s_src[64];
  __shared__ float s_dist[64];
  float* s_m2 = (float*)s_w2;   // reused after GEMM: [64][129] f32 (33024B <= 34816B)

  int tid = threadIdx.x, lane = tid & 63, w = tid >> 6;
  int e0 = blockIdx.x * 64;

  if (tid < 64){
    s_dst[tid]  = dst_s[e0+tid];
    s_src[tid]  = src_s[e0+tid];
    s_dist[tid] = dist_s[e0+tid];
  }
  #pragma unroll
  for (int it=0; it<8; ++it){
    int idx = tid + it*256;
    int r = idx >> 4, c = (idx & 15)*8;
    *(bf16x8*)&s_w2[r*136 + c] = *(const bf16x8*)(w2t + r*128 + c);
  }
  __syncthreads();

  // m1 = silu(A[dst] + B[src] + dist*w1r + b1), bf16 into LDS
  #pragma unroll
  for (int it=0; it<4; ++it){
    int idx = tid + it*256;
    int e = idx >> 4, c = (idx & 15)*8;
    int d = s_dst[e], s = s_src[e];
    float dist = s_dist[e];
    bf16x8 pa = *(const bf16x8*)(P + (size_t)d*256 + c);
    bf16x8 pb = *(const bf16x8*)(P + (size_t)s*256 + 128 + c);
    f32x4 wr0 = *(const f32x4*)(w1r + c);
    f32x4 wr1 = *(const f32x4*)(w1r + c + 4);
    f32x4 bb0 = *(const f32x4*)(b1 + c);
    f32x4 bb1 = *(const f32x4*)(b1 + c + 4);
    bf16x8 mm;
    #pragma unroll
    for (int j=0;j<4;++j){
      float pre = (float)pa[j] + (float)pb[j] + dist*wr0[j] + bb0[j];
      mm[j] = (bf16)silu_f(pre);
    }
    #pragma unroll
    for (int j=0;j<4;++j){
      float pre = (float)pa[4+j] + (float)pb[4+j] + dist*wr1[j] + bb1[j];
      mm[4+j] = (bf16)silu_f(pre);
    }
    *(bf16x8*)&s_m1[e*136 + c] = mm;
  }
  __syncthreads();

  // GEMM: wave w owns edges [w*16, w*16+16), all 128 output cols
  f32x4 acc[8];
  #pragma unroll
  for (int n=0;n<8;++n){
    #pragma unroll
    for (int r=0;r<4;++r) acc[n][r]=0.f;
  }
  int rsel = lane & 15, ksel = (lane>>4)*8;
  int arow = (w*16 + rsel)*136;
  #pragma unroll
  for (int ks=0;ks<4;++ks){
    int kb = ks*32 + ksel;
    bf16x8 af = *(const bf16x8*)&s_m1[arow + kb];
    #pragma unroll
    for (int n=0;n<8;++n){
      bf16x8 bfv = *(const bf16x8*)&s_w2[(n*16+rsel)*136 + kb];
      acc[n] = mfma16(af, bfv, acc[n]);
    }
  }
  __syncthreads();   // all reads of s_w2 done before aliasing as s_m2

  // m2 = silu(acc + b2) -> LDS [64][129] f32
  #pragma unroll
  for (int n=0;n<8;++n){
    int col = n*16 + rsel;
    float bv = b2[col];
    #pragma unroll
    for (int r=0;r<4;++r){
      int erow = w*16 + 4*(lane>>4) + r;
      s_m2[erow*129 + col] = silu_f(acc[n][r] + bv);
    }
  }
  __syncthreads();

  // segmented reduction over sorted dst; one atomic per run boundary
  int f = tid & 127, half = tid >> 7;
  int eb = half*32;
  float a = 0.f; int cur = s_dst[eb];
  #pragma unroll 1
  for (int e2=eb; e2<eb+32; ++e2){
    int d2 = s_dst[e2];
    float v = s_m2[e2*129 + f];
    if (d2 != cur){
      atomicAdd(&aggr[(size_t)cur*128 + f], a);
      a = v; cur = d2;
    } else a += v;
  }
  atomicAdd(&aggr[(size_t)cur*128 + f], a);
}

// ---------------- per-graph mean pooling ----------------
__device__ __forceinline__ int lbound(const int* a, int n, int key){
  int lo=0, hi=n;
  while (lo<hi){ int mid=(lo+hi)>>1; if (a[mid]<key) lo=mid+1; else hi=mid; }
  return lo;
}
__global__ __launch_bounds__(128) void k_pool(const float* __restrict__ h,
    const int* __restrict__ batch, float* __restrict__ g)
{
  int gr = blockIdx.x, f = threadIdx.x;
  int lo = lbound(batch, NN, gr), hi = lbound(batch, NN, gr+1);
  float s = 0.f;
  for (int n=lo;n<hi;++n) s += h[(size_t)n*HH + f];
  int c = hi - lo; if (c < 1) c = 1;
  g[gr*HH + f] = s / (float)c;
}

// ---------------- transformer (fp32, G=256) ----------------
__global__ __launch_bounds__(128) void k_qkv(
    const float* __restrict__ g, const float* __restrict__ wq,
    const float* __restrict__ bq, float* __restrict__ qkv)
{
  __shared__ float sg[128];
  int r = blockIdx.x, tid = threadIdx.x;
  sg[tid] = g[r*128 + tid];
  __syncthreads();
  float a0 = bq[tid], a1 = bq[tid+128], a2 = bq[tid+256];
  for (int k=0;k<128;++k){
    float gv = sg[k];
    const float* wr = wq + k*384;
    a0 += gv*wr[tid]; a1 += gv*wr[tid+128]; a2 += gv*wr[tid+256];
  }
  qkv[r*384+tid]=a0; qkv[r*384+tid+128]=a1; qkv[r*384+tid+256]=a2;
}

__global__ __launch_bounds__(128) void k_attn(
    const float* __restrict__ qkv, float* __restrict__ o)
{
  __shared__ float sq[128];
  __shared__ float ss[4][256];
  int r = blockIdx.x, tid = threadIdx.x;
  sq[tid] = qkv[r*384 + tid];
  __syncthreads();
  const float scale = 0.17677669529663687f; // 1/sqrt(32)
  for (int i=tid; i<1024; i+=128){
    int hh = i >> 8, j = i & 255;
    const float* kr = qkv + j*384 + 128 + hh*32;
    const float* qr = sq + hh*32;
    float s=0;
    #pragma unroll
    for (int d=0;d<32;++d) s += qr[d]*kr[d];
    ss[hh][j] = s*scale;
  }
  __syncthreads();
  int hh = tid >> 5, sl = tid & 31;
  float m = -1e30f;
  #pragma unroll
  for (int q8=0;q8<8;++q8) m = fmaxf(m, ss[hh][sl + q8*32]);
  #pragma unroll
  for (int off=16; off; off>>=1) m = fmaxf(m, __shfl_xor(m, off, 32));
  float sum = 0.f;
  #pragma unroll
  for (int q8=0;q8<8;++q8){
    float e = __expf(ss[hh][sl+q8*32] - m);
    ss[hh][sl+q8*32] = e;
    sum += e;
  }
  #pragma unroll
  for (int off=16; off; off>>=1) sum += __shfl_xor(sum, off, 32);
  float inv = 1.0f / sum;
  __syncthreads();
  float accv = 0.f;
  for (int j=0;j<256;++j) accv += ss[hh][j]*qkv[j*384 + 256 + hh*32 + sl];
  o[r*128 + hh*32 + sl] = accv*inv;
}

__global__ __launch_bounds__(128) void k_proj_ln(
    const float* __restrict__ o, const float* __restrict__ wo,
    const float* __restrict__ bo, const float* __restrict__ lg,
    const float* __restrict__ lb, float* __restrict__ g)
{
  __shared__ float so[128];
  __shared__ float red[4];
  int r = blockIdx.x, tid = threadIdx.x;
  so[tid] = o[r*128+tid];
  __syncthreads();
  float a = bo[tid];
  for (int k=0;k<128;++k) a += so[k]*wo[k*128 + tid];
  float val = g[r*128+tid] + a;
  float s = val, q = val*val;
  #pragma unroll
  for (int off=32; off; off>>=1){ s += __shfl_xor(s, off); q += __shfl_xor(q, off); }
  int lane = tid & 63, wv = tid >> 6;
  if (lane==0){ red[wv*2]=s; red[wv*2+1]=q; }
  __syncthreads();
  float S = red[0]+red[2], Q = red[1]+red[3];
  float mean = S*(1.0f/128.0f);
  float var = Q*(1.0f/128.0f) - mean*mean;
  float ninv = rsqrtf(var + 1e-5f);
  g[r*128+tid] = (val-mean)*ninv*lg[tid] + lb[tid];
}

__global__ __launch_bounds__(128) void k_ff1(
    const float* __restrict__ g, const float* __restrict__ w1,
    const float* __restrict__ b1f, float* __restrict__ t1)
{
  __shared__ float sg[128];
  int r = blockIdx.x, tid = threadIdx.x;
  sg[tid] = g[r*128+tid];
  __syncthreads();
  float a0 = b1f[tid], a1 = b1f[tid+128];
  for (int k=0;k<128;++k){
    float gv = sg[k];
    a0 += gv*w1[k*256 + tid];
    a1 += gv*w1[k*256 + tid + 128];
  }
  t1[r*256+tid]     = fmaxf(a0, 0.f);
  t1[r*256+tid+128] = fmaxf(a1, 0.f);
}

__global__ __launch_bounds__(128) void k_ff2_ln(
    const float* __restrict__ t1, const float* __restrict__ w2,
    const float* __restrict__ b2f, const float* __restrict__ lg,
    const float* __restrict__ lb, float* __restrict__ g)
{
  __shared__ float st[256];
  __shared__ float red[4];
  int r = blockIdx.x, tid = threadIdx.x;
  st[tid]     = t1[r*256+tid];
  st[tid+128] = t1[r*256+tid+128];
  __syncthreads();
  float a = b2f[tid];
  for (int k=0;k<256;++k) a += st[k]*w2[k*128 + tid];
  float val = g[r*128+tid] + a;
  float s = val, q = val*val;
  #pragma unroll
  for (int off=32; off; off>>=1){ s += __shfl_xor(s, off); q += __shfl_xor(q, off); }
  int lane = tid & 63, wv = tid >> 6;
  if (lane==0){ red[wv*2]=s; red[wv*2+1]=q; }
  __syncthreads();
  float S = red[0]+red[2], Q = red[1]+red[3];
  float mean = S*(1.0f/128.0f);
  float var = Q*(1.0f/128.0f) - mean*mean;
  float ninv = rsqrtf(var + 1e-5f);
  g[r*128+tid] = (val-mean)*ninv*lg[tid] + lb[tid];
}

__global__ __launch_bounds__(64) void k_cls(
    const float* __restrict__ g, const float* __restrict__ w1,
    const float* __restrict__ b1c, const float* __restrict__ w2,
    const float* __restrict__ b2c, float* __restrict__ out)
{
  __shared__ float sg[128];
  int r = blockIdx.x, tid = threadIdx.x;
  sg[tid]    = g[r*128+tid];
  sg[tid+64] = g[r*128+tid+64];
  __syncthreads();
  float a = b1c[tid];
  for (int k=0;k<128;++k) a += sg[k]*w1[k*64 + tid];
  a = fmaxf(a, 0.f);
  float p = a * w2[tid];
  #pragma unroll
  for (int off=32; off; off>>=1) p += __shfl_xor(p, off);
  if (tid==0) out[r] = p + b2c[0];
}

// ---------------- launch ----------------
extern "C" void kernel_launch(void* const* d_in, const int* in_sizes, int n_in,
                              void* d_out, int out_size, void* d_ws, size_t ws_size,
                              hipStream_t stream)
{
  (void)in_sizes; (void)n_in; (void)out_size; (void)ws_size;
  const float* x      = (const float*)d_in[0];
  const float* pos    = (const float*)d_in[1];
  const float* emb_w  = (const float*)d_in[2];
  const float* emb_b  = (const float*)d_in[3];
  const float* edge_w1= (const float*)d_in[4];
  const float* edge_b1= (const float*)d_in[5];
  const float* edge_w2= (const float*)d_in[6];
  const float* edge_b2= (const float*)d_in[7];
  const float* node_w1= (const float*)d_in[8];
  const float* node_b1= (const float*)d_in[9];
  const float* node_w2= (const float*)d_in[10];
  const float* node_b2= (const float*)d_in[11];
  const float* qkv_w  = (const float*)d_in[12];
  const float* qkv_b  = (const float*)d_in[13];
  const float* out_w  = (const float*)d_in[14];
  const float* out_b  = (const float*)d_in[15];
  const float* ln1_g  = (const float*)d_in[16];
  const float* ln1_b  = (const float*)d_in[17];
  const float* ln2_g  = (const float*)d_in[18];
  const float* ln2_b  = (const float*)d_in[19];
  const float* ff_w1  = (const float*)d_in[20];
  const float* ff_b1  = (const float*)d_in[21];
  const float* ff_w2  = (const float*)d_in[22];
  const float* ff_b2  = (const float*)d_in[23];
  const float* cls_w1 = (const float*)d_in[24];
  const float* cls_b1 = (const float*)d_in[25];
  const float* cls_w2 = (const float*)d_in[26];
  const float* cls_b2 = (const float*)d_in[27];
  const int* ei       = (const int*)d_in[28];
  const int* batch    = (const int*)d_in[29];
  float* out = (float*)d_out;

  uint8_t* wp = (uint8_t*)d_ws;
  auto take = [&](size_t nb)->void*{ void* r = wp; wp += (nb + 255) & ~(size_t)255; return r; };
  float* h      = (float*)take((size_t)NN*HH*4);
  bf16*  P      = (bf16*) take((size_t)NN*256*2);
  float* aggr   = (float*)take((size_t)NN*HH*4);
  bf16*  u1     = (bf16*) take((size_t)NN*HH*2);
  int*   cnt    = (int*)  take((size_t)NN*4);
  int*   cursor = (int*)  take((size_t)NN*4);
  int*   src_s  = (int*)  take((size_t)EE*4);
  int*   dst_s  = (int*)  take((size_t)EE*4);
  float* dist_s = (float*)take((size_t)EE*4);
  bf16*  wcatT  = (bf16*) take((size_t)3*256*128*2);
  bf16*  w2T    = (bf16*) take((size_t)3*128*128*2);
  bf16*  nw1T   = (bf16*) take((size_t)3*128*256*2);
  bf16*  nw2T   = (bf16*) take((size_t)3*128*128*2);
  float* gbuf   = (float*)take((size_t)GG*HH*4);
  float* qkvb   = (float*)take((size_t)GG*384*4);
  float* obuf   = (float*)take((size_t)GG*HH*4);
  float* t1buf  = (float*)take((size_t)GG*256*4);

  dim3 b256(256);
  hipMemsetAsync(cnt, 0, (size_t)NN*4, stream);
  // weight prep (all to [n][k] bf16)
  k_transpose_bf16<<<dim3(64,3), b256, 0, stream>>>(edge_w1,           wcatT,           128,128, 257*128, 256*128);
  k_transpose_bf16<<<dim3(64,3), b256, 0, stream>>>(edge_w1 + 128*128, wcatT + 128*128, 128,128, 257*128, 256*128);
  k_transpose_bf16<<<dim3(64,3), b256, 0, stream>>>(edge_w2,           w2T,             128,128, 128*128, 128*128);
  k_transpose_bf16<<<dim3(128,3), b256, 0, stream>>>(node_w1,          nw1T,            256,128, 256*128, 128*256);
  k_transpose_bf16<<<dim3(64,3), b256, 0, stream>>>(node_w2,           nw2T,            128,128, 128*128, 128*128);
  k_emb<<<dim3(NN*128/256), b256, 0, stream>>>(x, emb_w, emb_b, h);
  k_hist<<<dim3(EE/256), b256, 0, stream>>>(ei + EE, cnt);
  k_scan<<<dim3(1), dim3(1024), 0, stream>>>(cnt, cursor, NN);
  k_scatter<<<dim3(EE/256), b256, 0, stream>>>(ei, pos, cursor, src_s, dst_s, dist_s);

  for (int l=0;l<3;++l){
    // P = h @ [W1_dst | W1_src]  -> bf16 [N][256]
    k_gemm<128,128,0,false,false,false,true,false><<<dim3(625,4), b256, 0, stream>>>(
      h, nullptr, wcatT + (size_t)l*256*128, nullptr, nullptr, P, nullptr, 256);
    hipMemsetAsync(aggr, 0, (size_t)NN*128*4, stream);
    k_edge<<<dim3(EE/64), b256, 0, stream>>>(P, w2T + (size_t)l*128*128,
      edge_w1 + ((size_t)l*257 + 256)*128, edge_b1 + (size_t)l*128, edge_b2 + (size_t)l*128,
      src_s, dst_s, dist_s, aggr);
    // u1 = silu([h | aggr] @ node_w1 + b1)
    k_gemm<256,128,1,false,true,false,true,false><<<dim3(625,2), b256, 0, stream>>>(
      h, aggr, nw1T + (size_t)l*128*256, node_b1 + (size_t)l*128, nullptr, u1, nullptr, 128);
    // h = h + (u1 @ node_w2 + b2)
    k_gemm<128,128,0,true,true,true,false,true><<<dim3(625,2), b256, 0, stream>>>(
      u1, nullptr, nw2T + (size_t)l*128*128, node_b2 + (size_t)l*128, h, nullptr, h, 128);
  }

  k_pool<<<dim3(GG), dim3(128), 0, stream>>>(h, batch, gbuf);
  for (int t=0;t<2;++t){
    k_qkv<<<dim3(GG), dim3(128), 0, stream>>>(gbuf, qkv_w + (size_t)t*128*384, qkv_b + (size_t)t*384, qkvb);
    k_attn<<<dim3(GG), dim3(128), 0, stream>>>(qkvb, obuf);
    k_proj_ln<<<dim3(GG), dim3(128), 0, stream>>>(obuf, out_w + (size_t)t*128*128, out_b + (size_t)t*128,
      ln1_g + (size_t)t*128, ln1_b + (size_t)t*128, gbuf);
    k_ff1<<<dim3(GG), dim3(128), 0, stream>>>(gbuf, ff_w1 + (size_t)t*128*256, ff_b1 + (size_t)t*256, t1buf);
    k_ff2_ln<<<dim3(GG), dim3(128), 0, stream>>>(t1buf, ff_w2 + (size_t)t*256*128, ff_b2 + (size_t)t*128,
      ln2_g + (size_t)t*128, ln2_b + (size_t)t*128, gbuf);
  }
  k_cls<<<dim3(GG), dim3(64), 0, stream>>>(gbuf, cls_w1, cls_b1, cls_w2, cls_b2, out);
}